// Round 8
// baseline (180.383 us; speedup 1.0000x reference)
//
#include <hip/hip_runtime.h>
#include <hip/hip_bf16.h>
#include <math.h>

namespace {
constexpr int B_N = 4, T_N = 128, P_N = 256, D_N = 512, S_N = 64;
constexpr int NTH = 512;
constexpr int KC  = 32;
constexpr int NCH = D_N / KC;   // 16 k-chunks
constexpr size_t NROWS = (size_t)B_N * T_N * P_N;   // 131072 flat rows

// ---- K1 LDS (double-buffered staging only) ----
constexpr int XS0_OFF = 0;       // bf16 [128][32] swz32
constexpr int WS0_OFF = 8192;    // bf16 [208][32] swz32 (rows 200-207 zeroed)
constexpr int XS1_OFF = 21504;
constexpr int WS1_OFF = 29696;
constexpr int K1_LDS  = 43008;

// ---- K3 LDS ----
constexpr int ROS_OFF = 0;       // bf16 [128][64] swz64 (ro pass tile)
constexpr int CH3_OFF = 16384;   // bf16 [128][64] swz64 (CH tile)
constexpr int K3_LDS  = 32768;

// ---- fallback fused kernel LDS (round-7 layout) ----
constexpr int FXS0_OFF = 0;
constexpr int FWS0_OFF = 8192;
constexpr int FXS1_OFF = 21504;
constexpr int FWS1_OFF = 29696;
constexpr int FBU_OFF  = 0;
constexpr int FCH_OFF  = 16384;
constexpr int FROS_OFF = 0;
constexpr int FDT_OFF  = 43008;
constexpr int F_LDS    = 43520;
}

typedef short bf16x8 __attribute__((ext_vector_type(8)));
typedef float f32x4  __attribute__((ext_vector_type(4)));

__device__ __forceinline__ unsigned short f2b(float f) {
    unsigned int x = __float_as_uint(f);
    return (unsigned short)((x + 0x7FFFu + ((x >> 16) & 1u)) >> 16);  // RNE
}
__device__ __forceinline__ float b2f(unsigned short h) {
    return __uint_as_float(((unsigned int)h) << 16);
}
__device__ __forceinline__ unsigned int pk2(float lo, float hi) {
    union { __hip_bfloat162 h; unsigned int u; } cv;
    cv.h = __float22bfloat162_rn(float2{lo, hi});
    return cv.u;
}
__device__ __forceinline__ int swz32(int row, int col) {
    return row * 32 + (col ^ (((row >> 1) & 3) << 3));
}
__device__ __forceinline__ int swz64(int row, int col) {
    return row * 64 + (col ^ ((row & 7) << 3));
}
__device__ __forceinline__ void cvtstore8(unsigned short* dst, float4 a, float4 b) {
    uint4 r;
    r.x = pk2(a.x, a.y); r.y = pk2(a.z, a.w);
    r.z = pk2(b.x, b.y); r.w = pk2(b.z, b.w);
    *(uint4*)dst = r;
}

// =================== K1: projection GEMM (flat contiguous rows) ===================
__global__ __launch_bounds__(NTH, 4) void mamba_proj(
    const float* __restrict__ X,
    const float* __restrict__ U_w, const float* __restrict__ sB_w, const float* __restrict__ sB_b,
    const float* __restrict__ sC_w, const float* __restrict__ sC_b,
    const float* __restrict__ sD1_w, const float* __restrict__ sD1_b,
    const float* __restrict__ sD2_w, const float* __restrict__ sD2_b,
    unsigned short* __restrict__ BUCH, unsigned short* __restrict__ CG,
    float* __restrict__ DTW)
{
    __shared__ __align__(16) char smem[K1_LDS];
    unsigned short* XS0 = (unsigned short*)(smem + XS0_OFF);
    unsigned short* WS0 = (unsigned short*)(smem + WS0_OFF);
    unsigned short* XS1 = (unsigned short*)(smem + XS1_OFF);
    unsigned short* WS1 = (unsigned short*)(smem + WS1_OFF);

    const int tid  = threadIdx.x;
    const int lane = tid & 63;
    const int wid  = tid >> 6;
    const int wm   = wid >> 2;
    const int wn   = wid & 3;
    const int l15  = lane & 15;
    const int lg   = lane >> 4;
    const size_t row0 = (size_t)blockIdx.x * 128;

    if (tid < 128) {
        ((unsigned int*)(WS0 + 200 * 32))[tid] = 0;
        ((unsigned int*)(WS1 + 200 * 32))[tid] = 0;
    }

    f32x4 acc[4][3];
    f32x4 accdt;
    #pragma unroll
    for (int q = 0; q < 4; ++q) accdt[q] = 0.0f;
    #pragma unroll
    for (int mf = 0; mf < 4; ++mf)
        #pragma unroll
        for (int nf = 0; nf < 3; ++nf)
            #pragma unroll
            for (int q = 0; q < 4; ++q) acc[mf][nf][q] = 0.0f;

    // X staging: rows row0..row0+127 fully contiguous in memory
    const int xr = tid >> 2, xq = tid & 3;
    const float* xsrc = X + (row0 + xr) * D_N + xq * 8;
    const int xoff = swz32(xr, xq * 8);

    // W staging (interleaved rows: g*16+w, triple=g%3 (U,B,C), s=(g/3)*16+w; 192-199=sD1)
    const int wr0 = tid >> 2, wq = tid & 3;
    const int wr1 = 128 + wr0;
    const bool hasW1 = (tid < 288);
    const float* wsrc0;
    {
        int g = wr0 >> 4, w = wr0 & 15, tr = g % 3, sb = g / 3;
        const float* base = (tr == 0) ? U_w : (tr == 1) ? sB_w : sC_w;
        wsrc0 = base + (size_t)(sb * 16 + w) * D_N + wq * 8;
    }
    const float* wsrc1;
    if (wr1 < 192) {
        int g = wr1 >> 4, w = wr1 & 15, tr = g % 3, sb = g / 3;
        const float* base = (tr == 0) ? U_w : (tr == 1) ? sB_w : sC_w;
        wsrc1 = base + (size_t)(sb * 16 + w) * D_N + wq * 8;
    } else if (wr1 < 200) {
        wsrc1 = sD1_w + (size_t)(wr1 - 192) * D_N + wq * 8;
    } else {
        wsrc1 = wsrc0;
    }
    const int woff0 = swz32(wr0, wq * 8);
    const int woff1 = swz32(wr1 < 208 ? wr1 : 0, wq * 8);

    float4 xA = *(const float4*)(xsrc),   xB = *(const float4*)(xsrc + 4);
    float4 wA0 = *(const float4*)(wsrc0), wB0 = *(const float4*)(wsrc0 + 4);
    float4 wA1 = *(const float4*)(wsrc1), wB1 = *(const float4*)(wsrc1 + 4);
    cvtstore8(&XS0[xoff],  xA, xB);
    cvtstore8(&WS0[woff0], wA0, wB0);
    if (hasW1) cvtstore8(&WS0[woff1], wA1, wB1);
    {
        const float* nx = xsrc + KC;
        xA = *(const float4*)(nx); xB = *(const float4*)(nx + 4);
        const float* n0 = wsrc0 + KC;
        wA0 = *(const float4*)(n0); wB0 = *(const float4*)(n0 + 4);
        const float* n1 = wsrc1 + KC;
        wA1 = *(const float4*)(n1); wB1 = *(const float4*)(n1 + 4);
    }
    __syncthreads();

    const int kb = lg * 8;
    #pragma unroll 2
    for (int kc = 0; kc < NCH; ++kc) {
        unsigned short* XSc = (kc & 1) ? XS1 : XS0;
        unsigned short* WSc = (kc & 1) ? WS1 : WS0;
        unsigned short* XSn = (kc & 1) ? XS0 : XS1;
        unsigned short* WSn = (kc & 1) ? WS0 : WS1;
        if (kc + 1 < NCH) {
            cvtstore8(&XSn[xoff],  xA, xB);
            cvtstore8(&WSn[woff0], wA0, wB0);
            if (hasW1) cvtstore8(&WSn[woff1], wA1, wB1);
        }
        if (kc + 2 < NCH) {
            const float* nx = xsrc + (kc + 2) * KC;
            xA = *(const float4*)(nx); xB = *(const float4*)(nx + 4);
            const float* n0 = wsrc0 + (kc + 2) * KC;
            wA0 = *(const float4*)(n0); wB0 = *(const float4*)(n0 + 4);
            const float* n1 = wsrc1 + (kc + 2) * KC;
            wA1 = *(const float4*)(n1); wB1 = *(const float4*)(n1 + 4);
        }
        __builtin_amdgcn_s_setprio(1);
        bf16x8 a[4];
        #pragma unroll
        for (int mf = 0; mf < 4; ++mf)
            a[mf] = *(const bf16x8*)&XSc[swz32(wm * 64 + mf * 16 + l15, kb)];
        #pragma unroll
        for (int nf = 0; nf < 3; ++nf) {
            bf16x8 bb = *(const bf16x8*)&WSc[swz32(wn * 48 + nf * 16 + l15, kb)];
            #pragma unroll
            for (int mf = 0; mf < 4; ++mf)
                acc[mf][nf] = __builtin_amdgcn_mfma_f32_16x16x32_bf16(a[mf], bb, acc[mf][nf], 0, 0, 0);
        }
        {
            bf16x8 adt = *(const bf16x8*)&XSc[swz32(wid * 16 + l15, kb)];
            bf16x8 bd  = *(const bf16x8*)&WSc[swz32(192 + l15, kb)];
            accdt = __builtin_amdgcn_mfma_f32_16x16x32_bf16(adt, bd, accdt, 0, 0, 0);
        }
        __builtin_amdgcn_s_setprio(0);
        __syncthreads();
    }

    // epilogue: write BU=(B+bias)*u, C+bias to global (bf16); dt to global (f32)
    {
        const int s = wn * 16 + l15;
        const float biasB = sB_b[s], biasC = sC_b[s];
        #pragma unroll
        for (int mf = 0; mf < 4; ++mf) {
            #pragma unroll
            for (int q = 0; q < 4; ++q) {
                const size_t r = row0 + wm * 64 + mf * 16 + lg * 4 + q;
                const float u  = acc[mf][0][q];
                const float Bv = acc[mf][1][q] + biasB;
                const float Cv = acc[mf][2][q] + biasC;
                BUCH[r * 64 + s] = f2b(Bv * u);
                CG[r * 64 + s]   = f2b(Cv);
            }
        }
    }
    {
        const float w2 = (l15 < 8) ? sD2_w[l15] : 0.0f;
        const float b1 = (l15 < 8) ? sD1_b[l15] : 0.0f;
        const float b2 = sD2_b[0];
        #pragma unroll
        for (int q = 0; q < 4; ++q) {
            float z = accdt[q] + b1;
            float w = (z / (1.0f + expf(-z))) * w2;
            w = (l15 < 8) ? w : 0.0f;
            w += __shfl_xor(w, 1);
            w += __shfl_xor(w, 2);
            w += __shfl_xor(w, 4);
            if (l15 == 0) {
                float zz = w + b2;
                DTW[row0 + wid * 16 + lg * 4 + q] = (zz > 20.0f) ? zz : log1pf(expf(zz));
            }
        }
    }
}

// =================== K2: sequential scan per (b,p) ===================
__global__ __launch_bounds__(64, 8) void mamba_scan(
    const float* __restrict__ H0, const float* __restrict__ a_hat,
    unsigned short* __restrict__ BUCH, const unsigned short* __restrict__ CG,
    const float* __restrict__ DTW,
    float* __restrict__ Hseq, float* __restrict__ HT)
{
    const int blk = blockIdx.x;
    const int b = blk >> 8, p = blk & 255;
    const int s = threadIdx.x;
    const size_t base = (size_t)b * T_N * P_N + p;   // flat row of t=0 (stride P_N per t)
    const size_t i0 = base * 64 + s;                 // elem index (stride 16384 per t)

    const float la  = -expf(a_hat[s]);
    const float h0v = H0[((size_t)b * P_N + p) * S_N + s];
    float Pcv = 1.0f, cv = 0.0f, Hv = 0.0f;

    float bu[4], cc[4], dtq[4];
    #pragma unroll
    for (int q = 0; q < 4; ++q) {
        const size_t ix = i0 + (size_t)q * (P_N * 64);
        bu[q]  = b2f(BUCH[ix]);
        cc[q]  = b2f(CG[ix]);
        dtq[q] = DTW[base + (size_t)q * P_N];
    }
    for (int t0 = 0; t0 < T_N; t0 += 4) {
        float nbu[4], ncc[4], ndt[4];
        if (t0 + 4 < T_N) {
            #pragma unroll
            for (int q = 0; q < 4; ++q) {
                const size_t ix = i0 + (size_t)(t0 + 4 + q) * (P_N * 64);
                nbu[q] = b2f(BUCH[ix]);
                ncc[q] = b2f(CG[ix]);
                ndt[q] = DTW[base + (size_t)(t0 + 4 + q) * P_N];
            }
        }
        #pragma unroll
        for (int q = 0; q < 4; ++q) {
            const int t = t0 + q;
            const float Av = expf(dtq[q] * la);
            const float bv = (1.0f - Av) * bu[q];
            Pcv *= fmaxf(Av, 1e-12f);                 // Pc = cumprod(max(A,eps))
            cv += bv * (1.0f / fmaxf(Pcv, 1e-12f));   // c += b * invP
            Hv = Pcv * (h0v + cv);
            const size_t ix = i0 + (size_t)t * (P_N * 64);
            Hseq[ix] = Hv;
            BUCH[ix] = f2b(cc[q] * Hv);               // CH = C*H in place over BU
        }
        #pragma unroll
        for (int q = 0; q < 4; ++q) { bu[q] = nbu[q]; cc[q] = ncc[q]; dtq[q] = ndt[q]; }
    }
    HT[((size_t)b * P_N + p) * S_N + s] = Hv;
}

// =================== K3: Y = CH(128x64) x ro^T(64x512), contiguous rows ===================
__global__ __launch_bounds__(NTH, 4) void mamba_ygemm(
    const unsigned short* __restrict__ CHG, const float* __restrict__ ro_w,
    float* __restrict__ Y)
{
    __shared__ __align__(16) char smem[K3_LDS];
    unsigned short* ROS = (unsigned short*)(smem + ROS_OFF);
    unsigned short* CHB = (unsigned short*)(smem + CH3_OFF);

    const int tid  = threadIdx.x;
    const int lane = tid & 63;
    const int wid  = tid >> 6;
    const int wm   = wid >> 2;
    const int wn   = wid & 3;
    const int l15  = lane & 15;
    const int lg   = lane >> 4;
    const size_t row0 = (size_t)blockIdx.x * 128;

    // stage CH tile (already bf16): each thread copies 32 B
    const int crow = tid >> 2, cq = tid & 3;
    {
        const uint4 v0 = *(const uint4*)(CHG + (row0 + crow) * 64 + cq * 16);
        const uint4 v1 = *(const uint4*)(CHG + (row0 + crow) * 64 + cq * 16 + 8);
        *(uint4*)&CHB[swz64(crow, cq * 16)]     = v0;
        *(uint4*)&CHB[swz64(crow, cq * 16 + 8)] = v1;
    }
    // issue ro pass-0 loads
    const int rrow = tid >> 2, rq = tid & 3;
    const float* rosrc = ro_w + (size_t)rrow * S_N + rq * 16;
    float4 r0a = *(const float4*)(rosrc);
    float4 r0b = *(const float4*)(rosrc + 4);
    float4 r0c = *(const float4*)(rosrc + 8);
    float4 r0d = *(const float4*)(rosrc + 12);
    __syncthreads();

    bf16x8 af0[4], af1[4];
    #pragma unroll
    for (int mf = 0; mf < 4; ++mf) {
        af0[mf] = *(const bf16x8*)&CHB[swz64(wm * 64 + mf * 16 + l15, lg * 8)];
        af1[mf] = *(const bf16x8*)&CHB[swz64(wm * 64 + mf * 16 + l15, 32 + lg * 8)];
    }
    cvtstore8(&ROS[swz64(rrow, rq * 16)],     r0a, r0b);
    cvtstore8(&ROS[swz64(rrow, rq * 16 + 8)], r0c, r0d);
    __syncthreads();

    for (int pp = 0; pp < 4; ++pp) {
        if (pp < 3) {
            const float* ns = ro_w + (size_t)((pp + 1) * 128 + rrow) * S_N + rq * 16;
            r0a = *(const float4*)(ns);
            r0b = *(const float4*)(ns + 4);
            r0c = *(const float4*)(ns + 8);
            r0d = *(const float4*)(ns + 12);
        }
        f32x4 yacc[4][2];
        #pragma unroll
        for (int mf = 0; mf < 4; ++mf)
            #pragma unroll
            for (int nf = 0; nf < 2; ++nf)
                #pragma unroll
                for (int q = 0; q < 4; ++q) yacc[mf][nf][q] = 0.0f;
        #pragma unroll
        for (int nf = 0; nf < 2; ++nf) {
            bf16x8 bb0 = *(const bf16x8*)&ROS[swz64(wn * 32 + nf * 16 + l15, lg * 8)];
            bf16x8 bb1 = *(const bf16x8*)&ROS[swz64(wn * 32 + nf * 16 + l15, 32 + lg * 8)];
            #pragma unroll
            for (int mf = 0; mf < 4; ++mf) {
                yacc[mf][nf] = __builtin_amdgcn_mfma_f32_16x16x32_bf16(af0[mf], bb0, yacc[mf][nf], 0, 0, 0);
                yacc[mf][nf] = __builtin_amdgcn_mfma_f32_16x16x32_bf16(af1[mf], bb1, yacc[mf][nf], 0, 0, 0);
            }
        }
        #pragma unroll
        for (int mf = 0; mf < 4; ++mf) {
            const size_t r = row0 + wm * 64 + mf * 16 + lg * 4;
            float* ybase = Y + r * D_N + pp * 128 + wn * 32 + l15;
            #pragma unroll
            for (int nf = 0; nf < 2; ++nf) {
                #pragma unroll
                for (int q = 0; q < 4; ++q)
                    ybase[(size_t)q * D_N + nf * 16] = yacc[mf][nf][q];
            }
        }
        __syncthreads();
        if (pp < 3) {
            cvtstore8(&ROS[swz64(rrow, rq * 16)],     r0a, r0b);
            cvtstore8(&ROS[swz64(rrow, rq * 16 + 8)], r0c, r0d);
            __syncthreads();
        }
    }
}

// =================== Fallback: round-7 fused kernel (used if ws too small) ===================
__global__ __launch_bounds__(NTH, 4) void mamba_fused(
    const float* __restrict__ X, const float* __restrict__ H0,
    const float* __restrict__ a_hat,
    const float* __restrict__ U_w, const float* __restrict__ sB_w, const float* __restrict__ sB_b,
    const float* __restrict__ sC_w, const float* __restrict__ sC_b,
    const float* __restrict__ sD1_w, const float* __restrict__ sD1_b,
    const float* __restrict__ sD2_w, const float* __restrict__ sD2_b,
    const float* __restrict__ ro_w,
    float* __restrict__ Hseq, float* __restrict__ Y, float* __restrict__ HT)
{
    __shared__ __align__(16) char smem[F_LDS];
    unsigned short* XS0 = (unsigned short*)(smem + FXS0_OFF);
    unsigned short* WS0 = (unsigned short*)(smem + FWS0_OFF);
    unsigned short* XS1 = (unsigned short*)(smem + FXS1_OFF);
    unsigned short* WS1 = (unsigned short*)(smem + FWS1_OFF);
    unsigned short* BU  = (unsigned short*)(smem + FBU_OFF);
    unsigned short* ROS = (unsigned short*)(smem + FROS_OFF);
    unsigned short* CHB = (unsigned short*)(smem + FCH_OFF);
    float*          DTB = (float*)(smem + FDT_OFF);

    const int tid  = threadIdx.x;
    const int lane = tid & 63;
    const int wid  = tid >> 6;
    const int wm   = wid >> 2;
    const int wn   = wid & 3;
    const int l15  = lane & 15;
    const int lg   = lane >> 4;
    const int b    = blockIdx.x >> 8;
    const int p    = blockIdx.x & 255;

    const float la  = (tid < 64) ? -expf(a_hat[tid]) : 0.0f;
    const float h0v = (tid < 64) ? H0[((size_t)b * P_N + p) * S_N + tid] : 0.0f;

    if (tid < 128) {
        ((unsigned int*)(WS0 + 200 * 32))[tid] = 0;
        ((unsigned int*)(WS1 + 200 * 32))[tid] = 0;
    }

    f32x4 acc[4][3];
    f32x4 accdt;
    #pragma unroll
    for (int q = 0; q < 4; ++q) accdt[q] = 0.0f;
    #pragma unroll
    for (int mf = 0; mf < 4; ++mf)
        #pragma unroll
        for (int nf = 0; nf < 3; ++nf)
            #pragma unroll
            for (int q = 0; q < 4; ++q) acc[mf][nf][q] = 0.0f;

    const int xr = tid >> 2, xq = tid & 3;
    const float* xsrc = X + (((size_t)b * T_N + xr) * P_N + p) * D_N + xq * 8;
    const int xoff = swz32(xr, xq * 8);

    const int wr0 = tid >> 2, wq = tid & 3;
    const int wr1 = 128 + wr0;
    const bool hasW1 = (tid < 288);
    const float* wsrc0;
    {
        int g = wr0 >> 4, w = wr0 & 15, tr = g % 3, sb = g / 3;
        const float* base = (tr == 0) ? U_w : (tr == 1) ? sB_w : sC_w;
        wsrc0 = base + (size_t)(sb * 16 + w) * D_N + wq * 8;
    }
    const float* wsrc1;
    if (wr1 < 192) {
        int g = wr1 >> 4, w = wr1 & 15, tr = g % 3, sb = g / 3;
        const float* base = (tr == 0) ? U_w : (tr == 1) ? sB_w : sC_w;
        wsrc1 = base + (size_t)(sb * 16 + w) * D_N + wq * 8;
    } else if (wr1 < 200) {
        wsrc1 = sD1_w + (size_t)(wr1 - 192) * D_N + wq * 8;
    } else {
        wsrc1 = wsrc0;
    }
    const int woff0 = swz32(wr0, wq * 8);
    const int woff1 = swz32(wr1 < 208 ? wr1 : 0, wq * 8);

    float4 xA = *(const float4*)(xsrc),   xB = *(const float4*)(xsrc + 4);
    float4 wA0 = *(const float4*)(wsrc0), wB0 = *(const float4*)(wsrc0 + 4);
    float4 wA1 = *(const float4*)(wsrc1), wB1 = *(const float4*)(wsrc1 + 4);
    cvtstore8(&XS0[xoff],  xA, xB);
    cvtstore8(&WS0[woff0], wA0, wB0);
    if (hasW1) cvtstore8(&WS0[woff1], wA1, wB1);
    {
        const float* nx = xsrc + KC;
        xA = *(const float4*)(nx); xB = *(const float4*)(nx + 4);
        const float* n0 = wsrc0 + KC;
        wA0 = *(const float4*)(n0); wB0 = *(const float4*)(n0 + 4);
        const float* n1 = wsrc1 + KC;
        wA1 = *(const float4*)(n1); wB1 = *(const float4*)(n1 + 4);
    }
    __syncthreads();

    const int kb = lg * 8;
    #pragma unroll 2
    for (int kc = 0; kc < NCH; ++kc) {
        unsigned short* XSc = (kc & 1) ? XS1 : XS0;
        unsigned short* WSc = (kc & 1) ? WS1 : WS0;
        unsigned short* XSn = (kc & 1) ? XS0 : XS1;
        unsigned short* WSn = (kc & 1) ? WS0 : WS1;
        if (kc + 1 < NCH) {
            cvtstore8(&XSn[xoff],  xA, xB);
            cvtstore8(&WSn[woff0], wA0, wB0);
            if (hasW1) cvtstore8(&WSn[woff1], wA1, wB1);
        }
        if (kc + 2 < NCH) {
            const float* nx = xsrc + (kc + 2) * KC;
            xA = *(const float4*)(nx); xB = *(const float4*)(nx + 4);
            const float* n0 = wsrc0 + (kc + 2) * KC;
            wA0 = *(const float4*)(n0); wB0 = *(const float4*)(n0 + 4);
            const float* n1 = wsrc1 + (kc + 2) * KC;
            wA1 = *(const float4*)(n1); wB1 = *(const float4*)(n1 + 4);
        }
        __builtin_amdgcn_s_setprio(1);
        bf16x8 a[4];
        #pragma unroll
        for (int mf = 0; mf < 4; ++mf)
            a[mf] = *(const bf16x8*)&XSc[swz32(wm * 64 + mf * 16 + l15, kb)];
        #pragma unroll
        for (int nf = 0; nf < 3; ++nf) {
            bf16x8 bb = *(const bf16x8*)&WSc[swz32(wn * 48 + nf * 16 + l15, kb)];
            #pragma unroll
            for (int mf = 0; mf < 4; ++mf)
                acc[mf][nf] = __builtin_amdgcn_mfma_f32_16x16x32_bf16(a[mf], bb, acc[mf][nf], 0, 0, 0);
        }
        {
            bf16x8 adt = *(const bf16x8*)&XSc[swz32(wid * 16 + l15, kb)];
            bf16x8 bd  = *(const bf16x8*)&WSc[swz32(192 + l15, kb)];
            accdt = __builtin_amdgcn_mfma_f32_16x16x32_bf16(adt, bd, accdt, 0, 0, 0);
        }
        __builtin_amdgcn_s_setprio(0);
        __syncthreads();
    }

    {
        const int s = wn * 16 + l15;
        const float biasB = sB_b[s], biasC = sC_b[s];
        #pragma unroll
        for (int mf = 0; mf < 4; ++mf) {
            #pragma unroll
            for (int q = 0; q < 4; ++q) {
                const int t = wm * 64 + mf * 16 + lg * 4 + q;
                const float u  = acc[mf][0][q];
                const float Bv = acc[mf][1][q] + biasB;
                const float Cv = acc[mf][2][q] + biasC;
                BU[t * 64 + s]   = f2b(Bv * u);
                CHB[swz64(t, s)] = f2b(Cv);
            }
        }
    }
    {
        const float w2 = (l15 < 8) ? sD2_w[l15] : 0.0f;
        const float b1 = (l15 < 8) ? sD1_b[l15] : 0.0f;
        const float b2 = sD2_b[0];
        #pragma unroll
        for (int q = 0; q < 4; ++q) {
            float z = accdt[q] + b1;
            float w = (z / (1.0f + expf(-z))) * w2;
            w = (l15 < 8) ? w : 0.0f;
            w += __shfl_xor(w, 1);
            w += __shfl_xor(w, 2);
            w += __shfl_xor(w, 4);
            if (l15 == 0) {
                float zz = w + b2;
                DTB[wid * 16 + lg * 4 + q] = (zz > 20.0f) ? zz : log1pf(expf(zz));
            }
        }
    }
    __syncthreads();

    const int rrow = tid >> 2, rq = tid & 3;
    const float* rosrc = ro_w + (size_t)rrow * S_N + rq * 16;
    float4 r0a = *(const float4*)(rosrc);
    float4 r0b = *(const float4*)(rosrc + 4);
    float4 r0c = *(const float4*)(rosrc + 8);
    float4 r0d = *(const float4*)(rosrc + 12);

    if (tid < 64) {
        const int s = tid;
        float Pcv = 1.0f, cv = 0.0f, Hv = 0.0f;
        float* hout = Hseq + ((size_t)b * T_N * P_N + p) * S_N + s;
        for (int t = 0; t < T_N; ++t) {
            const float Av = expf(DTB[t] * la);
            const float bv = (1.0f - Av) * b2f(BU[t * 64 + s]);
            Pcv *= fmaxf(Av, 1e-12f);
            cv += bv * (1.0f / fmaxf(Pcv, 1e-12f));
            Hv = Pcv * (h0v + cv);
            hout[(size_t)t * P_N * S_N] = Hv;
            const int e = swz64(t, s);
            CHB[e] = f2b(b2f(CHB[e]) * Hv);
        }
        HT[((size_t)b * P_N + p) * S_N + s] = Hv;
    }
    __syncthreads();

    bf16x8 af0[4], af1[4];
    #pragma unroll
    for (int mf = 0; mf < 4; ++mf) {
        af0[mf] = *(const bf16x8*)&CHB[swz64(wm * 64 + mf * 16 + l15, lg * 8)];
        af1[mf] = *(const bf16x8*)&CHB[swz64(wm * 64 + mf * 16 + l15, 32 + lg * 8)];
    }
    cvtstore8(&ROS[swz64(rrow, rq * 16)],     r0a, r0b);
    cvtstore8(&ROS[swz64(rrow, rq * 16 + 8)], r0c, r0d);
    __syncthreads();

    for (int pp = 0; pp < 4; ++pp) {
        if (pp < 3) {
            const float* ns = ro_w + (size_t)((pp + 1) * 128 + rrow) * S_N + rq * 16;
            r0a = *(const float4*)(ns);
            r0b = *(const float4*)(ns + 4);
            r0c = *(const float4*)(ns + 8);
            r0d = *(const float4*)(ns + 12);
        }
        f32x4 yacc[4][2];
        #pragma unroll
        for (int mf = 0; mf < 4; ++mf)
            #pragma unroll
            for (int nf = 0; nf < 2; ++nf)
                #pragma unroll
                for (int q = 0; q < 4; ++q) yacc[mf][nf][q] = 0.0f;
        #pragma unroll
        for (int nf = 0; nf < 2; ++nf) {
            bf16x8 bb0 = *(const bf16x8*)&ROS[swz64(wn * 32 + nf * 16 + l15, lg * 8)];
            bf16x8 bb1 = *(const bf16x8*)&ROS[swz64(wn * 32 + nf * 16 + l15, 32 + lg * 8)];
            #pragma unroll
            for (int mf = 0; mf < 4; ++mf) {
                yacc[mf][nf] = __builtin_amdgcn_mfma_f32_16x16x32_bf16(af0[mf], bb0, yacc[mf][nf], 0, 0, 0);
                yacc[mf][nf] = __builtin_amdgcn_mfma_f32_16x16x32_bf16(af1[mf], bb1, yacc[mf][nf], 0, 0, 0);
            }
        }
        #pragma unroll
        for (int mf = 0; mf < 4; ++mf) {
            const int t0 = wm * 64 + mf * 16 + lg * 4;
            float* ybase = Y + (((size_t)b * T_N + t0) * P_N + p) * D_N + pp * 128 + wn * 32 + l15;
            #pragma unroll
            for (int nf = 0; nf < 2; ++nf) {
                #pragma unroll
                for (int q = 0; q < 4; ++q)
                    ybase[(size_t)q * P_N * D_N + nf * 16] = yacc[mf][nf][q];
            }
        }
        __syncthreads();
        if (pp < 3) {
            cvtstore8(&ROS[swz64(rrow, rq * 16)],     r0a, r0b);
            cvtstore8(&ROS[swz64(rrow, rq * 16 + 8)], r0c, r0d);
            __syncthreads();
        }
    }
}

extern "C" void kernel_launch(void* const* d_in, const int* in_sizes, int n_in,
                              void* d_out, int out_size, void* d_ws, size_t ws_size,
                              hipStream_t stream) {
    const float* X     = (const float*)d_in[0];
    const float* H0    = (const float*)d_in[1];
    const float* a_hat = (const float*)d_in[2];
    const float* U_w   = (const float*)d_in[3];
    const float* sB_w  = (const float*)d_in[4];
    const float* sB_b  = (const float*)d_in[5];
    const float* sC_w  = (const float*)d_in[6];
    const float* sC_b  = (const float*)d_in[7];
    const float* sD1_w = (const float*)d_in[8];
    const float* sD1_b = (const float*)d_in[9];
    const float* sD2_w = (const float*)d_in[10];
    const float* sD2_b = (const float*)d_in[11];
    const float* ro_w  = (const float*)d_in[12];

    float* out   = (float*)d_out;
    float* HseqP = out;
    float* YP    = out + (size_t)B_N * T_N * P_N * S_N;
    float* HTP   = YP  + (size_t)B_N * T_N * P_N * D_N;

    const size_t buBytes = NROWS * 64 * 2;          // 16.78 MB
    const size_t wsNeed  = 2 * buBytes + NROWS * 4; // 34.08 MB

    if (ws_size >= wsNeed) {
        unsigned short* BUCH = (unsigned short*)d_ws;
        unsigned short* CG   = (unsigned short*)((char*)d_ws + buBytes);
        float*          DTW  = (float*)((char*)d_ws + 2 * buBytes);

        hipLaunchKernelGGL(mamba_proj, dim3(1024), dim3(NTH), 0, stream,
                           X, U_w, sB_w, sB_b, sC_w, sC_b,
                           sD1_w, sD1_b, sD2_w, sD2_b, BUCH, CG, DTW);
        hipLaunchKernelGGL(mamba_scan, dim3(1024), dim3(64), 0, stream,
                           H0, a_hat, BUCH, CG, DTW, HseqP, HTP);
        hipLaunchKernelGGL(mamba_ygemm, dim3(1024), dim3(NTH), 0, stream,
                           BUCH, ro_w, YP);
    } else {
        hipLaunchKernelGGL(mamba_fused, dim3(B_N * P_N), dim3(NTH), 0, stream,
                           X, H0, a_hat, U_w, sB_w, sB_b, sC_w, sC_b,
                           sD1_w, sD1_b, sD2_w, sD2_b, ro_w, HseqP, YP, HTP);
    }
}

// Round 9
// 153.744 us; speedup vs baseline: 1.1733x; 1.1733x over previous
//
#include <hip/hip_runtime.h>
#include <hip/hip_bf16.h>
#include <math.h>

namespace {
constexpr int B_N = 4, T_N = 128, P_N = 256, D_N = 512, S_N = 64;
constexpr int NTH = 512;
constexpr int KC  = 32;
constexpr int NCH = D_N / KC;   // 16 k-chunks

// LDS (bytes). Liveness (barrier-protected):
//   phase1 k-loop : XS0 [0,8192) WS0 [8192,24576) XS1 [24576,32768) WS1 [32768,49152)
//   epilogue+scan : BU [0,16384) + CHB [16384,32768) + ROS0 [32768,49152) (staged during scan)
//   phase3        : ROS0 [32768,49152) / ROS1 [0,16384) double-buffer + CHB
constexpr int XS0_OFF = 0;       // bf16 [128][32] swz32
constexpr int WS0_OFF = 8192;    // bf16 [256][32] swz32 image copy (rows 200-255 zero)
constexpr int XS1_OFF = 24576;
constexpr int WS1_OFF = 32768;
constexpr int BU_OFF  = 0;       // bf16 [128][64] linear
constexpr int CH_OFF  = 16384;   // bf16 [128][64] swz64
constexpr int ROS0_OFF= 32768;   // bf16 [128][64] swz64 image copy
constexpr int ROS1_OFF= 0;
constexpr int DT_OFF  = 49152;   // f32 [128]
constexpr int LDS_BYTES = 49664; // 2 blocks/CU (99.3 KB)

// ws images
constexpr int WIMG_ELEMS  = NCH * 256 * 32;   // 131072 bf16 (16 chunks x [256][32] swz32)
constexpr int ROIMG_ELEMS = 4 * 128 * 64;     // 32768 bf16 (4 passes x [128][64] swz64)
}

typedef short bf16x8 __attribute__((ext_vector_type(8)));
typedef float f32x4  __attribute__((ext_vector_type(4)));

__device__ __forceinline__ unsigned short f2b(float f) {
    unsigned int x = __float_as_uint(f);
    return (unsigned short)((x + 0x7FFFu + ((x >> 16) & 1u)) >> 16);  // RNE
}
__device__ __forceinline__ float b2f(unsigned short h) {
    return __uint_as_float(((unsigned int)h) << 16);
}
__device__ __forceinline__ unsigned int pk2(float lo, float hi) {
    union { __hip_bfloat162 h; unsigned int u; } cv;
    cv.h = __float22bfloat162_rn(float2{lo, hi});
    return cv.u;
}
__device__ __forceinline__ int swz32(int row, int col) {
    return row * 32 + (col ^ (((row >> 1) & 3) << 3));
}
__device__ __forceinline__ int swz64(int row, int col) {
    return row * 64 + (col ^ ((row & 7) << 3));
}
__device__ __forceinline__ void cvtstore8(unsigned short* dst, float4 a, float4 b) {
    uint4 r;
    r.x = pk2(a.x, a.y); r.y = pk2(a.z, a.w);
    r.z = pk2(b.x, b.y); r.w = pk2(b.z, b.w);
    *(uint4*)dst = r;
}

// ===== K0: build swizzled bf16 images of weights and ro in ws =====
__global__ __launch_bounds__(512) void mamba_prep(
    const float* __restrict__ U_w, const float* __restrict__ sB_w,
    const float* __restrict__ sC_w, const float* __restrict__ sD1_w,
    const float* __restrict__ ro_w,
    unsigned short* __restrict__ wImg, unsigned short* __restrict__ roImg)
{
    const int idx = blockIdx.x * 512 + threadIdx.x;
    if (idx < WIMG_ELEMS) {
        const int kc = idx >> 13, rem = idx & 8191, r = rem >> 5, c = rem & 31;
        float v = 0.0f;
        if (r < 192) {
            const int g = r >> 4, w = r & 15, tr = g % 3, sb = g / 3;
            const float* base = (tr == 0) ? U_w : (tr == 1) ? sB_w : sC_w;
            v = base[(size_t)(sb * 16 + w) * D_N + kc * KC + c];
        } else if (r < 200) {
            v = sD1_w[(size_t)(r - 192) * D_N + kc * KC + c];
        }
        wImg[kc * 8192 + swz32(r, c)] = f2b(v);
    } else if (idx < WIMG_ELEMS + ROIMG_ELEMS) {
        const int j = idx - WIMG_ELEMS;
        const int pp = j >> 13, rem = j & 8191, r = rem >> 6, c = rem & 63;
        roImg[pp * 8192 + swz64(r, c)] = f2b(ro_w[(size_t)(pp * 128 + r) * S_N + c]);
    }
}

// ===== fused kernel =====
__global__ __launch_bounds__(NTH, 4) void mamba_mfma(
    const float* __restrict__ X, const float* __restrict__ H0,
    const float* __restrict__ a_hat,
    const float* __restrict__ sB_b, const float* __restrict__ sC_b,
    const float* __restrict__ sD1_b, const float* __restrict__ sD2_w,
    const float* __restrict__ sD2_b,
    const unsigned short* __restrict__ wImg, const unsigned short* __restrict__ roImg,
    float* __restrict__ Hseq, float* __restrict__ Y, float* __restrict__ HT)
{
    __shared__ __align__(16) char smem[LDS_BYTES];
    float* DTB = (float*)(smem + DT_OFF);

    const int tid  = threadIdx.x;
    const int lane = tid & 63;
    const int wid  = tid >> 6;
    const int wm   = wid >> 2;     // 0..1
    const int wn   = wid & 3;      // 0..3
    const int l15  = lane & 15;
    const int lg   = lane >> 4;    // 0..3
    const int b    = blockIdx.x >> 8;
    const int p    = blockIdx.x & 255;

    // scan-wave constants hoisted (issued early; hide under phase 1)
    const float la  = (tid < 64) ? -expf(a_hat[tid]) : 0.0f;
    const float h0v = (tid < 64) ? H0[((size_t)b * P_N + p) * S_N + tid] : 0.0f;

    // ---------------- Phase 1: projections, M=128(t) N=192(+8 dt) K=512 ----------------
    f32x4 acc[4][3];
    f32x4 accdt;
    #pragma unroll
    for (int q = 0; q < 4; ++q) accdt[q] = 0.0f;
    #pragma unroll
    for (int mf = 0; mf < 4; ++mf)
        #pragma unroll
        for (int nf = 0; nf < 3; ++nf)
            #pragma unroll
            for (int q = 0; q < 4; ++q) acc[mf][nf][q] = 0.0f;

    // X staging: 128 rows x 4 quads of 8 f32 (cvt on write)
    const int xr = tid >> 2, xq = tid & 3;
    const float* xsrc = X + (((size_t)b * T_N + xr) * P_N + p) * D_N + xq * 8;
    const int xoff = swz32(xr, xq * 8);

    // W staging: pure 32B copy per thread from pre-swizzled image
    const char* wImgB = (const char*)wImg;

    float4 xA = *(const float4*)(xsrc), xB = *(const float4*)(xsrc + 4);
    uint4 wpA = *((const uint4*)(wImgB) + tid * 2);
    uint4 wpB = *((const uint4*)(wImgB) + tid * 2 + 1);
    cvtstore8((unsigned short*)(smem + XS0_OFF) + xoff, xA, xB);
    *((uint4*)(smem + WS0_OFF) + tid * 2)     = wpA;
    *((uint4*)(smem + WS0_OFF) + tid * 2 + 1) = wpB;
    {
        const float* nx = xsrc + KC;
        xA = *(const float4*)(nx); xB = *(const float4*)(nx + 4);
        wpA = *((const uint4*)(wImgB + 16384) + tid * 2);
        wpB = *((const uint4*)(wImgB + 16384) + tid * 2 + 1);
    }
    __syncthreads();

    const int kb = lg * 8;
    #pragma unroll 2
    for (int kc = 0; kc < NCH; ++kc) {
        unsigned short* XSc = (unsigned short*)(smem + ((kc & 1) ? XS1_OFF : XS0_OFF));
        unsigned short* WSc = (unsigned short*)(smem + ((kc & 1) ? WS1_OFF : WS0_OFF));
        char*           XSn = smem + ((kc & 1) ? XS0_OFF : XS1_OFF);
        char*           WSn = smem + ((kc & 1) ? WS0_OFF : WS1_OFF);
        if (kc + 1 < NCH) {
            cvtstore8((unsigned short*)XSn + xoff, xA, xB);
            *((uint4*)WSn + tid * 2)     = wpA;
            *((uint4*)WSn + tid * 2 + 1) = wpB;
        }
        if (kc + 2 < NCH) {
            const float* nx = xsrc + (kc + 2) * KC;
            xA = *(const float4*)(nx); xB = *(const float4*)(nx + 4);
            wpA = *((const uint4*)(wImgB + (kc + 2) * 16384) + tid * 2);
            wpB = *((const uint4*)(wImgB + (kc + 2) * 16384) + tid * 2 + 1);
        }
        __builtin_amdgcn_s_setprio(1);
        bf16x8 a[4];
        #pragma unroll
        for (int mf = 0; mf < 4; ++mf)
            a[mf] = *(const bf16x8*)&XSc[swz32(wm * 64 + mf * 16 + l15, kb)];
        #pragma unroll
        for (int nf = 0; nf < 3; ++nf) {
            bf16x8 bb = *(const bf16x8*)&WSc[swz32(wn * 48 + nf * 16 + l15, kb)];
            #pragma unroll
            for (int mf = 0; mf < 4; ++mf)
                acc[mf][nf] = __builtin_amdgcn_mfma_f32_16x16x32_bf16(a[mf], bb, acc[mf][nf], 0, 0, 0);
        }
        {   // dt frag: this wave's 16 t-rows; B rows 192-199 = sD1, 200-207 = baked zeros
            bf16x8 adt = *(const bf16x8*)&XSc[swz32(wid * 16 + l15, kb)];
            bf16x8 bd  = *(const bf16x8*)&WSc[swz32(192 + l15, kb)];
            accdt = __builtin_amdgcn_mfma_f32_16x16x32_bf16(adt, bd, accdt, 0, 0, 0);
        }
        __builtin_amdgcn_s_setprio(0);
        __syncthreads();
    }

    // ---------------- Phase 1 epilogue ----------------
    // C/D frag: col=lane&15, row=(lane>>4)*4+reg (m89-verified)
    {
        unsigned short* BU  = (unsigned short*)(smem + BU_OFF);
        unsigned short* CHB = (unsigned short*)(smem + CH_OFF);
        const int s = wn * 16 + l15;
        const float biasB = sB_b[s], biasC = sC_b[s];
        #pragma unroll
        for (int mf = 0; mf < 4; ++mf) {
            #pragma unroll
            for (int q = 0; q < 4; ++q) {
                const int t = wm * 64 + mf * 16 + lg * 4 + q;
                const float u  = acc[mf][0][q];
                const float Bv = acc[mf][1][q] + biasB;
                const float Cv = acc[mf][2][q] + biasC;
                BU[t * 64 + s]   = f2b(Bv * u);
                CHB[swz64(t, s)] = f2b(Cv);
            }
        }
    }
    {
        const float w2 = (l15 < 8) ? sD2_w[l15] : 0.0f;
        const float b1 = (l15 < 8) ? sD1_b[l15] : 0.0f;
        const float b2 = sD2_b[0];
        #pragma unroll
        for (int q = 0; q < 4; ++q) {
            float z = accdt[q] + b1;
            float w = (z / (1.0f + expf(-z))) * w2;
            w = (l15 < 8) ? w : 0.0f;
            w += __shfl_xor(w, 1);
            w += __shfl_xor(w, 2);
            w += __shfl_xor(w, 4);
            if (l15 == 0) {
                float zz = w + b2;
                DTB[wid * 16 + lg * 4 + q] = (zz > 20.0f) ? zz : log1pf(expf(zz));
            }
        }
    }
    __syncthreads();

    // ---------------- Phase 2: scan (wave 0) || ROS0 pass-0 copy (waves 1-7) ----------------
    if (tid < 64) {
        unsigned short* BU  = (unsigned short*)(smem + BU_OFF);
        unsigned short* CHB = (unsigned short*)(smem + CH_OFF);
        const int s = tid;
        float Pcv = 1.0f, cv = 0.0f, Hv = 0.0f;
        float* hout = Hseq + ((size_t)b * T_N * P_N + p) * S_N + s;
        for (int t = 0; t < T_N; ++t) {
            const float Av = expf(DTB[t] * la);
            const float bv = (1.0f - Av) * b2f(BU[t * 64 + s]);
            Pcv *= fmaxf(Av, 1e-12f);                 // Pc = cumprod(max(A,eps))
            cv += bv * (1.0f / fmaxf(Pcv, 1e-12f));   // c += b * invP
            Hv = Pcv * (h0v + cv);
            hout[(size_t)t * P_N * S_N] = Hv;
            const int e = swz64(t, s);
            CHB[e] = f2b(b2f(CHB[e]) * Hv);           // CH = C*H
        }
        HT[((size_t)b * P_N + p) * S_N + s] = Hv;
    } else {
        // copy ro pass-0 tile (16 KB) into ROS0 while the scan runs
        for (int u = tid - 64; u < 512; u += 448) {
            uint4 a0 = *((const uint4*)roImg + u * 2);
            uint4 a1 = *((const uint4*)roImg + u * 2 + 1);
            *((uint4*)(smem + ROS0_OFF) + u * 2)     = a0;
            *((uint4*)(smem + ROS0_OFF) + u * 2 + 1) = a1;
        }
    }
    __syncthreads();

    // ---------------- Phase 3: Y = CH(128x64) x ro^T(64x512), ROS double-buffered ----------------
    bf16x8 af0[4], af1[4];
    {
        unsigned short* CHB = (unsigned short*)(smem + CH_OFF);
        #pragma unroll
        for (int mf = 0; mf < 4; ++mf) {
            af0[mf] = *(const bf16x8*)&CHB[swz64(wm * 64 + mf * 16 + l15, lg * 8)];
            af1[mf] = *(const bf16x8*)&CHB[swz64(wm * 64 + mf * 16 + l15, 32 + lg * 8)];
        }
    }

    for (int pp = 0; pp < 4; ++pp) {
        unsigned short* cur = (unsigned short*)(smem + ((pp & 1) ? ROS1_OFF : ROS0_OFF));
        char*           nxt = smem + ((pp & 1) ? ROS0_OFF : ROS1_OFF);
        uint4 npA, npB;
        if (pp < 3) {   // load next pass tile regs (32 B/thread)
            const uint4* s = (const uint4*)((const char*)roImg + (pp + 1) * 16384) + tid * 2;
            npA = s[0]; npB = s[1];
        }
        f32x4 yacc[4][2];
        #pragma unroll
        for (int mf = 0; mf < 4; ++mf)
            #pragma unroll
            for (int nf = 0; nf < 2; ++nf)
                #pragma unroll
                for (int q = 0; q < 4; ++q) yacc[mf][nf][q] = 0.0f;
        #pragma unroll
        for (int nf = 0; nf < 2; ++nf) {
            bf16x8 bb0 = *(const bf16x8*)&cur[swz64(wn * 32 + nf * 16 + l15, lg * 8)];
            bf16x8 bb1 = *(const bf16x8*)&cur[swz64(wn * 32 + nf * 16 + l15, 32 + lg * 8)];
            #pragma unroll
            for (int mf = 0; mf < 4; ++mf) {
                yacc[mf][nf] = __builtin_amdgcn_mfma_f32_16x16x32_bf16(af0[mf], bb0, yacc[mf][nf], 0, 0, 0);
                yacc[mf][nf] = __builtin_amdgcn_mfma_f32_16x16x32_bf16(af1[mf], bb1, yacc[mf][nf], 0, 0, 0);
            }
        }
        if (pp < 3) {   // write next tile into the other buffer (its readers finished last pass)
            *((uint4*)nxt + tid * 2)     = npA;
            *((uint4*)nxt + tid * 2 + 1) = npB;
        }
        #pragma unroll
        for (int mf = 0; mf < 4; ++mf) {
            const int t0 = wm * 64 + mf * 16 + lg * 4;
            float* ybase = Y + (((size_t)b * T_N + t0) * P_N + p) * D_N + pp * 128 + wn * 32 + l15;
            #pragma unroll
            for (int nf = 0; nf < 2; ++nf) {
                #pragma unroll
                for (int q = 0; q < 4; ++q)
                    ybase[(size_t)q * P_N * D_N + nf * 16] = yacc[mf][nf][q];
            }
        }
        if (pp < 3) __syncthreads();
    }
}

extern "C" void kernel_launch(void* const* d_in, const int* in_sizes, int n_in,
                              void* d_out, int out_size, void* d_ws, size_t ws_size,
                              hipStream_t stream) {
    const float* X     = (const float*)d_in[0];
    const float* H0    = (const float*)d_in[1];
    const float* a_hat = (const float*)d_in[2];
    const float* U_w   = (const float*)d_in[3];
    const float* sB_w  = (const float*)d_in[4];
    const float* sB_b  = (const float*)d_in[5];
    const float* sC_w  = (const float*)d_in[6];
    const float* sC_b  = (const float*)d_in[7];
    const float* sD1_w = (const float*)d_in[8];
    const float* sD1_b = (const float*)d_in[9];
    const float* sD2_w = (const float*)d_in[10];
    const float* sD2_b = (const float*)d_in[11];
    const float* ro_w  = (const float*)d_in[12];

    float* out   = (float*)d_out;
    float* HseqP = out;
    float* YP    = out + (size_t)B_N * T_N * P_N * S_N;
    float* HTP   = YP  + (size_t)B_N * T_N * P_N * D_N;

    unsigned short* wImg  = (unsigned short*)d_ws;                       // 262144 B
    unsigned short* roImg = (unsigned short*)((char*)d_ws + 262144);     // 65536 B

    hipLaunchKernelGGL(mamba_prep, dim3((WIMG_ELEMS + ROIMG_ELEMS) / 512), dim3(512), 0, stream,
                       U_w, sB_w, sC_w, sD1_w, ro_w, wImg, roImg);
    hipLaunchKernelGGL(mamba_mfma, dim3(B_N * P_N), dim3(NTH), 0, stream,
                       X, H0, a_hat, sB_b, sC_b, sD1_b, sD2_w, sD2_b,
                       wImg, roImg, HseqP, YP, HTP);
}